// Round 5
// baseline (299.037 us; speedup 1.0000x reference)
//
#include <hip/hip_runtime.h>

typedef __bf16 bf16_t;
typedef __bf16 bf16x8 __attribute__((ext_vector_type(8)));
typedef __bf16 bf16x4 __attribute__((ext_vector_type(4)));
typedef float  f32x4  __attribute__((ext_vector_type(4)));

// workspace layout (bf16 element offsets)
#define WB_OFF  0LL          // 3 x 1024 x 1024 bf16 weights (q,k,v)
#define XQT_OFF 3145728LL    // [b][p][c] bf16
#define XKT_OFF 11534336LL
#define Q_OFF   19922944LL   // [b][c][p] bf16
#define KT_OFF  28311552LL   // [b][p][c] bf16
#define VT_OFF  36700160LL   // [b][p][c] bf16
// total: 45088768 elems * 2B = 90.2 MB

__device__ __forceinline__ void gl_lds16(const bf16_t* g, bf16_t* l) {
  __builtin_amdgcn_global_load_lds((const __attribute__((address_space(1))) void*)(g),
                                   (__attribute__((address_space(3))) void*)(l), 16, 0, 0);
}

__device__ __forceinline__ bf16x4 cvt4(f32x4 v) {
  bf16x4 r;
  r[0] = (bf16_t)v[0]; r[1] = (bf16_t)v[1]; r[2] = (bf16_t)v[2]; r[3] = (bf16_t)v[3];
  return r;
}

// ---------------- weight convert: fp32 -> bf16 ----------------
__global__ __launch_bounds__(256) void k_wconv(
    const float* __restrict__ Wq, const float* __restrict__ Wk, const float* __restrict__ Wv,
    bf16_t* __restrict__ ws)
{
  const float* W = blockIdx.y == 0 ? Wq : (blockIdx.y == 1 ? Wk : Wv);
  bf16_t* dst = ws + WB_OFF + (long)blockIdx.y * 1048576;
  const long i = ((long)blockIdx.x * 256 + threadIdx.x) * 4;
  *(bf16x4*)&dst[i] = cvt4(*(const f32x4*)(W + i));
}

// ---------------- transpose+convert: XT[b][p][c] = bf16(X[b][c][p]) ----------------
__global__ __launch_bounds__(256) void k_transpose(
    const float* __restrict__ Xq, const float* __restrict__ Xk, bf16_t* __restrict__ ws)
{
  __shared__ __align__(16) bf16_t t[64 * 72];  // +8 pad per row (16B-aligned rows)
  const int z = blockIdx.z, b = z & 3, ts = z >> 2;
  const float* X = ts ? Xk : Xq;
  bf16_t* XT = ws + (ts ? XKT_OFF : XQT_OFF);
  const int p0 = blockIdx.x * 64, c0 = blockIdx.y * 64;
  const int tid = threadIdx.x;
  const int tx = tid & 15, ty = tid >> 4;  // tx: float4 column, ty: 0..15
  const float* src = X + ((long)b * 1024 + c0) * 2048 + p0;
  #pragma unroll
  for (int hh = 0; hh < 4; ++hh) {
    int c = ty + hh * 16;
    f32x4 v = *(const f32x4*)(src + (long)c * 2048 + tx * 4);
    *(bf16x4*)&t[c * 72 + tx * 4] = cvt4(v);
  }
  __syncthreads();
  bf16_t* dst = XT + ((long)b * 2048 + p0) * 1024 + c0;
  #pragma unroll
  for (int hh = 0; hh < 2; ++hh) {
    int p = (tid >> 3) + hh * 32;  // 0..63
    int cc = tid & 7;
    bf16x8 v;
    #pragma unroll
    for (int j = 0; j < 8; ++j) v[j] = t[(cc * 8 + j) * 72 + p];
    *(bf16x8*)(dst + (long)p * 1024 + cc * 8) = v;
  }
}

// ---------------- QKV GEMM: Y[o][p] = LeakyReLU(BN(W @ X)) ----------------
__global__ __launch_bounds__(256) void k_qkv(
    const float* __restrict__ g1, const float* __restrict__ b1, const float* __restrict__ m1, const float* __restrict__ v1,
    const float* __restrict__ g2, const float* __restrict__ b2, const float* __restrict__ m2, const float* __restrict__ v2,
    const float* __restrict__ g3, const float* __restrict__ b3, const float* __restrict__ m3, const float* __restrict__ v3,
    bf16_t* __restrict__ ws)
{
  __shared__ __align__(16) bf16_t smem[17408];  // staging: a[8192]+b[8192]; epilogue: 128*136
  bf16_t* sa = smem;
  bf16_t* sb = smem + 8192;
  bf16_t* ep = smem;
  __shared__ float sS[128], sBi[128];

  const int tid = threadIdx.x;
  const int z = blockIdx.z, br = z >> 2, b = z & 3;
  const int o0 = blockIdx.y * 128, p0 = blockIdx.x * 128;

  const float *gm, *bt, *mn, *vr;
  const bf16_t *XT;
  bf16_t* dst;
  int tr;
  if (br == 0)      { XT = ws + XQT_OFF; gm = g1; bt = b1; mn = m1; vr = v1; dst = ws + Q_OFF;  tr = 0; }
  else if (br == 1) { XT = ws + XKT_OFF; gm = g2; bt = b2; mn = m2; vr = v2; dst = ws + KT_OFF; tr = 1; }
  else              { XT = ws + XQT_OFF; gm = g3; bt = b3; mn = m3; vr = v3; dst = ws + VT_OFF; tr = 1; }
  const bf16_t* W = ws + WB_OFF + (long)br * 1048576;

  if (tid < 128) {
    float g = gm[o0 + tid], be = bt[o0 + tid];
    float m = mn[o0 + tid], v = vr[o0 + tid];
    float sc = g / sqrtf(v + 1e-5f);
    sS[tid] = sc; sBi[tid] = be - m * sc;
  }

  const int w = tid >> 6, lane = tid & 63, quad = lane >> 4, l15 = lane & 15;
  const int wr = (w >> 1) * 64, wc = (w & 1) * 64;

  f32x4 acc[4][4];
  #pragma unroll
  for (int i = 0; i < 4; ++i)
    #pragma unroll
    for (int j = 0; j < 4; ++j) acc[i][j] = f32x4{0.f, 0.f, 0.f, 0.f};

  const bf16_t* Wb = W + (long)o0 * 1024;
  const bf16_t* Xb = XT + ((long)b * 2048 + p0) * 1024;

  for (int kk = 0; kk < 16; ++kk) {
    __syncthreads();
    const int kof = kk * 64;
    #pragma unroll
    for (int is = 0; is < 4; ++is) {
      int s = (is * 4 + w) * 64 + lane;
      int row = s >> 3, ch = s & 7;
      int col = kof + ((ch ^ (row & 7)) << 3);
      gl_lds16(Wb + (long)row * 1024 + col, &sa[(is * 4 + w) * 512]);
      gl_lds16(Xb + (long)row * 1024 + col, &sb[(is * 4 + w) * 512]);
    }
    __syncthreads();
    #pragma unroll
    for (int ks = 0; ks < 2; ++ks) {
      bf16x8 af[4], bfr[4];
      #pragma unroll
      for (int i = 0; i < 4; ++i) {
        int mm = wr + i * 16 + l15;
        af[i] = *(const bf16x8*)&sa[mm * 64 + (((ks * 4 + quad) ^ (mm & 7)) << 3)];
        int nn = wc + i * 16 + l15;
        bfr[i] = *(const bf16x8*)&sb[nn * 64 + (((ks * 4 + quad) ^ (nn & 7)) << 3)];
      }
      #pragma unroll
      for (int i = 0; i < 4; ++i)
        #pragma unroll
        for (int j = 0; j < 4; ++j)
          acc[i][j] = __builtin_amdgcn_mfma_f32_16x16x32_bf16(af[i], bfr[j], acc[i][j], 0, 0, 0);
    }
  }

  __syncthreads();
  #pragma unroll
  for (int i = 0; i < 4; ++i) {
    #pragma unroll
    for (int j = 0; j < 4; ++j) {
      const int p_l = wc + j * 16 + l15;
      const int ob = wr + i * 16 + quad * 4;
      if (!tr) {
        #pragma unroll
        for (int r = 0; r < 4; ++r) {
          float v = fmaf(acc[i][j][r], sS[ob + r], sBi[ob + r]);
          v = v > 0.f ? v : 0.1f * v;
          ep[(ob + r) * 136 + p_l] = (bf16_t)v;
        }
      } else {
        bf16x4 t4;
        #pragma unroll
        for (int r = 0; r < 4; ++r) {
          float v = fmaf(acc[i][j][r], sS[ob + r], sBi[ob + r]);
          v = v > 0.f ? v : 0.1f * v;
          t4[r] = (bf16_t)v;
        }
        *(bf16x4*)&ep[p_l * 136 + ob] = t4;  // (p_l*136+ob)*2 is 8B-aligned
      }
    }
  }
  __syncthreads();
  #pragma unroll
  for (int pass = 0; pass < 8; ++pass) {
    int row = pass * 16 + (tid >> 4);
    int ch = tid & 15;
    bf16x8 v = *(const bf16x8*)&ep[row * 136 + ch * 8];
    long off;
    if (!tr) off = ((long)b * 1024 + o0 + row) * 2048 + p0 + ch * 8;
    else     off = ((long)b * 2048 + p0 + row) * 1024 + o0 + ch * 8;
    *(bf16x8*)&dst[off] = v;
  }
}

// ---------------- fused attention v3: square wave tiles ----------------
// per block: (b, h, i0-tile of 128). 8 waves, TJ=64, 32 iters, 2 barriers/jt.
// S-phase: wave (iq=w&3, jg=w>>2) computes S^T tile [32 j][32 i]; V A-frags
// from LDS (8 b128), K B-frags register-resident (32 VGPR, loaded once from
// global). exp -> P[i][j] in LDS (cross-wave). U-phase: wave (iq, cg=jg)
// computes U tile [32 i][64 c]: P A-frags (4 b128) + Q B-frags (8 b128).
// LDS read amp per block per jt: 160 KB (was 272 KB) -> LDS-throughput relief.
// V/Q double-buffered via global_load_lds with incremental addresses.
__global__ __launch_bounds__(512, 4) void k_attn(const bf16_t* __restrict__ ws, float* __restrict__ out)
{
  __shared__ __align__(16) bf16_t sV[2][8192];   // [j 64][c 128] chunk-swizzled
  __shared__ __align__(16) bf16_t sQ[2][8192];   // [c 128][j 64] chunk-swizzled
  __shared__ __align__(16) bf16_t sP[8192];      // [i 128][j 64] chunk-swizzled

  const int tid = threadIdx.x, w = tid >> 6, lane = tid & 63, quad = lane >> 4, l15 = lane & 15;
  const int i0 = blockIdx.x * 128, h = blockIdx.y, b = blockIdx.z;

  const bf16_t* KTb = ws + KT_OFF + ((long)b * 2048 + i0) * 1024 + h * 128;
  const bf16_t* VTb = ws + VT_OFF + ((long)b * 2048) * 1024 + h * 128;
  const bf16_t* Qb  = ws + Q_OFF  + ((long)b * 1024 + h * 128) * 2048;

  const int iq = w & 3, jg = w >> 2;
  const int i0w = iq * 32, j0w = jg * 32, c0 = jg * 64;

  // resident K B-frags: kf[ng][kc] covers i = i0w+ng*16+l15, c = kc*32+quad*8+e
  bf16x8 kf[2][4];
  #pragma unroll
  for (int ng = 0; ng < 2; ++ng) {
    const bf16_t* kr = KTb + (long)(i0w + ng * 16 + l15) * 1024 + quad * 8;
    #pragma unroll
    for (int kc = 0; kc < 4; ++kc)
      kf[ng][kc] = *(const bf16x8*)(kr + kc * 32);
  }

  f32x4 U[2][4];
  #pragma unroll
  for (int ig = 0; ig < 2; ++ig)
    #pragma unroll
    for (int ng = 0; ng < 4; ++ng) U[ig][ng] = f32x4{0.f, 0.f, 0.f, 0.f};
  float ls2[2] = {0.f, 0.f};

  // incremental staging addresses (each thread: 2 V slots + 2 Q slots)
  const int sA = tid, sB = 512 + tid;
  const bf16_t* vgA = VTb + (long)(sA >> 4) * 1024 + (((sA & 15) ^ ((sA >> 4) & 15)) << 3);
  const bf16_t* vgB = VTb + (long)(sB >> 4) * 1024 + (((sB & 15) ^ ((sB >> 4) & 15)) << 3);
  const bf16_t* qgA = Qb + (long)(sA >> 3) * 2048 + (((sA & 7) ^ ((sA >> 3) & 7)) << 3);
  const bf16_t* qgB = Qb + (long)(sB >> 3) * 2048 + (((sB & 7) ^ ((sB >> 3) & 7)) << 3);

  auto stage = [&](int bb) {
    gl_lds16(vgA, &sV[bb][sA * 8]);
    gl_lds16(qgA, &sQ[bb][sA * 8]);
    gl_lds16(vgB, &sV[bb][sB * 8]);
    gl_lds16(qgB, &sQ[bb][sB * 8]);
    vgA += 65536; vgB += 65536;   // 64 rows * 1024
    qgA += 64;    qgB += 64;      // 64 cols
  };

  const float SCL = 1.4426950408889634f * 0.08838834764831843f;  // log2(e)/sqrt(128)

  stage(0);
  __syncthreads();

  for (int jt = 0; jt < 32; ++jt) {
    const int cur = jt & 1;
    if (jt < 31) stage(cur ^ 1);   // prefetch into free buffer; lands by next jt

    // ---- S-phase: S^T tiles [j0w+mg*16 .. +16)[i0w+ng*16 .. +16)
    const bf16_t* sVc = sV[cur];
    #pragma unroll
    for (int mg = 0; mg < 2; ++mg) {
      const int j = j0w + mg * 16 + l15;
      bf16x8 av[4];
      #pragma unroll
      for (int kc = 0; kc < 4; ++kc)
        av[kc] = *(const bf16x8*)&sVc[j * 128 + (((kc * 4 + quad) ^ l15) << 3)];
      #pragma unroll
      for (int ng = 0; ng < 2; ++ng) {
        f32x4 S = f32x4{0.f, 0.f, 0.f, 0.f};
        #pragma unroll
        for (int kc = 0; kc < 4; ++kc)
          S = __builtin_amdgcn_mfma_f32_16x16x32_bf16(av[kc], kf[ng][kc], S, 0, 0, 0);
        // D: row j = j0w+mg*16+quad*4+r, col i = i0w+ng*16+l15
        bf16x4 p4;
        #pragma unroll
        for (int r = 0; r < 4; ++r) {
          float p = exp2f(S[r] * SCL);
          ls2[ng] += p;
          p4[r] = (bf16_t)p;
        }
        const int i = i0w + ng * 16 + l15;
        const int jw = j0w + mg * 16 + quad * 4;
        *(bf16x4*)&sP[i * 64 + (((jw >> 3) ^ (i & 7)) << 3) + (jw & 7)] = p4;
      }
    }
    __syncthreads();   // P visible to all waves

    // ---- U-phase: U tiles [i0w+ig*16)[c0+ng*16), k = 64 j
    const bf16_t* sQc = sQ[cur];
    #pragma unroll
    for (int kj = 0; kj < 2; ++kj) {
      bf16x8 pa[2];
      #pragma unroll
      for (int ig = 0; ig < 2; ++ig) {
        const int i = i0w + ig * 16 + l15;
        pa[ig] = *(const bf16x8*)&sP[i * 64 + (((kj * 4 + quad) ^ (i & 7)) << 3)];
      }
      #pragma unroll
      for (int ng = 0; ng < 4; ++ng) {
        const int c = c0 + ng * 16 + l15;
        bf16x8 qf = *(const bf16x8*)&sQc[c * 64 + (((kj * 4 + quad) ^ (c & 7)) << 3)];
        #pragma unroll
        for (int ig = 0; ig < 2; ++ig)
          U[ig][ng] = __builtin_amdgcn_mfma_f32_16x16x32_bf16(pa[ig], qf, U[ig][ng], 0, 0, 0);
      }
    }
    __syncthreads();   // release sV/sQ[cur] for restage, sP for next S-phase
  }

  // ---- softmax denominators: ls2[ng] is partial for i = i0w+ng*16+l15 over jg's j
  #pragma unroll
  for (int ng = 0; ng < 2; ++ng) {
    ls2[ng] += __shfl_xor(ls2[ng], 16, 64);
    ls2[ng] += __shfl_xor(ls2[ng], 32, 64);
  }
  float* lsb = (float*)sP;   // [jg 2][i 128]
  if (lane < 16) {
    lsb[jg * 128 + i0w + lane] = ls2[0];
    lsb[jg * 128 + i0w + 16 + lane] = ls2[1];
  }
  __syncthreads();

  // ---- epilogue: out[b][h*128+c][i0+i], f32x4 along i
  #pragma unroll
  for (int ig = 0; ig < 2; ++ig) {
    f32x4 rcp;
    #pragma unroll
    for (int r = 0; r < 4; ++r) {
      const int i = i0w + ig * 16 + quad * 4 + r;
      rcp[r] = 1.0f / (lsb[i] + lsb[128 + i]);
    }
    #pragma unroll
    for (int ng = 0; ng < 4; ++ng) {
      const int c = h * 128 + c0 + ng * 16 + l15;
      f32x4 v;
      #pragma unroll
      for (int r = 0; r < 4; ++r) v[r] = U[ig][ng][r] * rcp[r];
      const long o = ((long)b * 1024 + c) * 2048 + i0 + i0w + ig * 16 + quad * 4;
      *(f32x4*)&out[o] = v;
    }
  }
}

extern "C" void kernel_launch(void* const* d_in, const int* in_sizes, int n_in,
                              void* d_out, int out_size, void* d_ws, size_t ws_size,
                              hipStream_t stream)
{
  (void)in_sizes; (void)n_in; (void)out_size; (void)ws_size;
  const float* Xq = (const float*)d_in[0];
  const float* Xk = (const float*)d_in[1];
  const float* Wq = (const float*)d_in[2];
  const float* Wk = (const float*)d_in[3];
  const float* Wv = (const float*)d_in[4];
  bf16_t* ws = (bf16_t*)d_ws;
  float* out = (float*)d_out;

  k_wconv<<<dim3(1024, 3), 256, 0, stream>>>(Wq, Wk, Wv, ws);
  k_transpose<<<dim3(32, 16, 8), 256, 0, stream>>>(Xq, Xk, ws);
  k_qkv<<<dim3(16, 8, 12), 256, 0, stream>>>(
      (const float*)d_in[5],  (const float*)d_in[6],  (const float*)d_in[7],  (const float*)d_in[8],
      (const float*)d_in[9],  (const float*)d_in[10], (const float*)d_in[11], (const float*)d_in[12],
      (const float*)d_in[13], (const float*)d_in[14], (const float*)d_in[15], (const float*)d_in[16],
      ws);
  k_attn<<<dim3(16, 8, 4), 512, 0, stream>>>(ws, out);
}

// Round 6
// 297.098 us; speedup vs baseline: 1.0065x; 1.0065x over previous
//
#include <hip/hip_runtime.h>

typedef __bf16 bf16_t;
typedef __bf16 bf16x8 __attribute__((ext_vector_type(8)));
typedef __bf16 bf16x4 __attribute__((ext_vector_type(4)));
typedef float  f32x4  __attribute__((ext_vector_type(4)));

// workspace layout (bf16 element offsets)
#define WB_OFF  0LL          // 3 x 1024 x 1024 bf16 weights (q,k,v)
#define XQT_OFF 3145728LL    // [b][p][c] bf16
#define XKT_OFF 11534336LL
#define Q_OFF   19922944LL   // [b][c][p] bf16
#define KT_OFF  28311552LL   // [b][p][c] bf16 (pre-scaled by log2(e)/sqrt(128))
#define VT_OFF  36700160LL   // [b][p][c] bf16
// total: 45088768 elems * 2B = 90.2 MB

__device__ __forceinline__ void gl_lds16(const bf16_t* g, bf16_t* l) {
  __builtin_amdgcn_global_load_lds((const __attribute__((address_space(1))) void*)(g),
                                   (__attribute__((address_space(3))) void*)(l), 16, 0, 0);
}

__device__ __forceinline__ bf16x4 cvt4(f32x4 v) {
  bf16x4 r;
  r[0] = (bf16_t)v[0]; r[1] = (bf16_t)v[1]; r[2] = (bf16_t)v[2]; r[3] = (bf16_t)v[3];
  return r;
}

#define ATT_SCL 0.1275973836582966f   // log2(e) / sqrt(128), folded into K branch

// ---------------- weight convert: fp32 -> bf16 ----------------
__global__ __launch_bounds__(256) void k_wconv(
    const float* __restrict__ Wq, const float* __restrict__ Wk, const float* __restrict__ Wv,
    bf16_t* __restrict__ ws)
{
  const float* W = blockIdx.y == 0 ? Wq : (blockIdx.y == 1 ? Wk : Wv);
  bf16_t* dst = ws + WB_OFF + (long)blockIdx.y * 1048576;
  const long i = ((long)blockIdx.x * 256 + threadIdx.x) * 4;
  *(bf16x4*)&dst[i] = cvt4(*(const f32x4*)(W + i));
}

// ---------------- transpose+convert: XT[b][p][c] = bf16(X[b][c][p]) ----------------
__global__ __launch_bounds__(256) void k_transpose(
    const float* __restrict__ Xq, const float* __restrict__ Xk, bf16_t* __restrict__ ws)
{
  __shared__ __align__(16) bf16_t t[64 * 72];  // +8 pad per row (16B-aligned rows)
  const int z = blockIdx.z, b = z & 3, ts = z >> 2;
  const float* X = ts ? Xk : Xq;
  bf16_t* XT = ws + (ts ? XKT_OFF : XQT_OFF);
  const int p0 = blockIdx.x * 64, c0 = blockIdx.y * 64;
  const int tid = threadIdx.x;
  const int tx = tid & 15, ty = tid >> 4;  // tx: float4 column, ty: 0..15
  const float* src = X + ((long)b * 1024 + c0) * 2048 + p0;
  #pragma unroll
  for (int hh = 0; hh < 4; ++hh) {
    int c = ty + hh * 16;
    f32x4 v = *(const f32x4*)(src + (long)c * 2048 + tx * 4);
    *(bf16x4*)&t[c * 72 + tx * 4] = cvt4(v);
  }
  __syncthreads();
  bf16_t* dst = XT + ((long)b * 2048 + p0) * 1024 + c0;
  #pragma unroll
  for (int hh = 0; hh < 2; ++hh) {
    int p = (tid >> 3) + hh * 32;  // 0..63
    int cc = tid & 7;
    bf16x8 v;
    #pragma unroll
    for (int j = 0; j < 8; ++j) v[j] = t[(cc * 8 + j) * 72 + p];
    *(bf16x8*)(dst + (long)p * 1024 + cc * 8) = v;
  }
}

// ---------------- QKV GEMM: Y[o][p] = LeakyReLU(BN(W @ X)) ----------------
__global__ __launch_bounds__(256) void k_qkv(
    const float* __restrict__ g1, const float* __restrict__ b1, const float* __restrict__ m1, const float* __restrict__ v1,
    const float* __restrict__ g2, const float* __restrict__ b2, const float* __restrict__ m2, const float* __restrict__ v2,
    const float* __restrict__ g3, const float* __restrict__ b3, const float* __restrict__ m3, const float* __restrict__ v3,
    bf16_t* __restrict__ ws)
{
  __shared__ __align__(16) bf16_t smem[17408];  // staging: a[8192]+b[8192]; epilogue: 128*136
  bf16_t* sa = smem;
  bf16_t* sb = smem + 8192;
  bf16_t* ep = smem;
  __shared__ float sS[128], sBi[128];

  const int tid = threadIdx.x;
  const int z = blockIdx.z, br = z >> 2, b = z & 3;
  const int o0 = blockIdx.y * 128, p0 = blockIdx.x * 128;

  const float *gm, *bt, *mn, *vr;
  const bf16_t *XT;
  bf16_t* dst;
  int tr;
  if (br == 0)      { XT = ws + XQT_OFF; gm = g1; bt = b1; mn = m1; vr = v1; dst = ws + Q_OFF;  tr = 0; }
  else if (br == 1) { XT = ws + XKT_OFF; gm = g2; bt = b2; mn = m2; vr = v2; dst = ws + KT_OFF; tr = 1; }
  else              { XT = ws + XQT_OFF; gm = g3; bt = b3; mn = m3; vr = v3; dst = ws + VT_OFF; tr = 1; }
  const bf16_t* W = ws + WB_OFF + (long)br * 1048576;

  if (tid < 128) {
    float g = gm[o0 + tid], be = bt[o0 + tid];
    float m = mn[o0 + tid], v = vr[o0 + tid];
    float sc = g / sqrtf(v + 1e-5f);
    float bi = be - m * sc;
    if (br == 1) { sc *= ATT_SCL; bi *= ATT_SCL; }   // fold attn scale into K branch
    sS[tid] = sc; sBi[tid] = bi;
  }

  const int w = tid >> 6, lane = tid & 63, quad = lane >> 4, l15 = lane & 15;
  const int wr = (w >> 1) * 64, wc = (w & 1) * 64;

  f32x4 acc[4][4];
  #pragma unroll
  for (int i = 0; i < 4; ++i)
    #pragma unroll
    for (int j = 0; j < 4; ++j) acc[i][j] = f32x4{0.f, 0.f, 0.f, 0.f};

  const bf16_t* Wb = W + (long)o0 * 1024;
  const bf16_t* Xb = XT + ((long)b * 2048 + p0) * 1024;

  for (int kk = 0; kk < 16; ++kk) {
    __syncthreads();
    const int kof = kk * 64;
    #pragma unroll
    for (int is = 0; is < 4; ++is) {
      int s = (is * 4 + w) * 64 + lane;
      int row = s >> 3, ch = s & 7;
      int col = kof + ((ch ^ (row & 7)) << 3);
      gl_lds16(Wb + (long)row * 1024 + col, &sa[(is * 4 + w) * 512]);
      gl_lds16(Xb + (long)row * 1024 + col, &sb[(is * 4 + w) * 512]);
    }
    __syncthreads();
    #pragma unroll
    for (int ks = 0; ks < 2; ++ks) {
      bf16x8 af[4], bfr[4];
      #pragma unroll
      for (int i = 0; i < 4; ++i) {
        int mm = wr + i * 16 + l15;
        af[i] = *(const bf16x8*)&sa[mm * 64 + (((ks * 4 + quad) ^ (mm & 7)) << 3)];
        int nn = wc + i * 16 + l15;
        bfr[i] = *(const bf16x8*)&sb[nn * 64 + (((ks * 4 + quad) ^ (nn & 7)) << 3)];
      }
      #pragma unroll
      for (int i = 0; i < 4; ++i)
        #pragma unroll
        for (int j = 0; j < 4; ++j)
          acc[i][j] = __builtin_amdgcn_mfma_f32_16x16x32_bf16(af[i], bfr[j], acc[i][j], 0, 0, 0);
    }
  }

  __syncthreads();
  #pragma unroll
  for (int i = 0; i < 4; ++i) {
    #pragma unroll
    for (int j = 0; j < 4; ++j) {
      const int p_l = wc + j * 16 + l15;
      const int ob = wr + i * 16 + quad * 4;
      if (!tr) {
        #pragma unroll
        for (int r = 0; r < 4; ++r) {
          float v = fmaf(acc[i][j][r], sS[ob + r], sBi[ob + r]);
          v = v > 0.f ? v : 0.1f * v;
          ep[(ob + r) * 136 + p_l] = (bf16_t)v;
        }
      } else {
        bf16x4 t4;
        #pragma unroll
        for (int r = 0; r < 4; ++r) {
          float v = fmaf(acc[i][j][r], sS[ob + r], sBi[ob + r]);
          v = v > 0.f ? v : 0.1f * v;
          t4[r] = (bf16_t)v;
        }
        *(bf16x4*)&ep[p_l * 136 + ob] = t4;  // (p_l*136+ob)*2 is 8B-aligned
      }
    }
  }
  __syncthreads();
  #pragma unroll
  for (int pass = 0; pass < 8; ++pass) {
    int row = pass * 16 + (tid >> 4);
    int ch = tid & 15;
    bf16x8 v = *(const bf16x8*)&ep[row * 136 + ch * 8];
    long off;
    if (!tr) off = ((long)b * 1024 + o0 + row) * 2048 + p0 + ch * 8;
    else     off = ((long)b * 2048 + p0 + row) * 1024 + o0 + ch * 8;
    *(bf16x8*)&dst[off] = v;
  }
}

// ---------------- fused attention v4: square tiles + VALU diet ----------------
// Same tiling as v3 (S^T 32x32 per wave, U 32x64 per wave, 2 barriers/jt).
// jt loop manually unrolled x2 so sV[half]/sQ[half] are compile-time bases:
// all LDS addresses become loop-invariant VGPRs (buffer 1 = same VGPR +
// offset:0x4000 immediate). exp via raw v_exp_f32 (scale pre-folded into K).
// waves_per_eu(4,4): occupancy is LDS-capped at 4 waves/EU, so let the
// allocator use the full 128-VGPR budget instead of recomputing addresses.
__global__ __launch_bounds__(512) __attribute__((amdgpu_waves_per_eu(4, 4)))
void k_attn(const bf16_t* __restrict__ ws, float* __restrict__ out)
{
  __shared__ __align__(16) bf16_t sV[2][8192];   // [j 64][c 128] chunk-swizzled
  __shared__ __align__(16) bf16_t sQ[2][8192];   // [c 128][j 64] chunk-swizzled
  __shared__ __align__(16) bf16_t sP[8192];      // [i 128][j 64] chunk-swizzled

  const int tid = threadIdx.x, w = tid >> 6, lane = tid & 63, quad = lane >> 4, l15 = lane & 15;
  const int i0 = blockIdx.x * 128, h = blockIdx.y, b = blockIdx.z;

  const bf16_t* KTb = ws + KT_OFF + ((long)b * 2048 + i0) * 1024 + h * 128;
  const bf16_t* VTb = ws + VT_OFF + ((long)b * 2048) * 1024 + h * 128;
  const bf16_t* Qb  = ws + Q_OFF  + ((long)b * 1024 + h * 128) * 2048;

  const int iq = w & 3, jg = w >> 2;
  const int i0w = iq * 32, j0w = jg * 32, c0 = jg * 64;

  // resident K B-frags: kf[ng][kc] covers i = i0w+ng*16+l15, c = kc*32+quad*8+e
  bf16x8 kf[2][4];
  #pragma unroll
  for (int ng = 0; ng < 2; ++ng) {
    const bf16_t* kr = KTb + (long)(i0w + ng * 16 + l15) * 1024 + quad * 8;
    #pragma unroll
    for (int kc = 0; kc < 4; ++kc)
      kf[ng][kc] = *(const bf16x8*)(kr + kc * 32);
  }

  f32x4 U[2][4];
  #pragma unroll
  for (int ig = 0; ig < 2; ++ig)
    #pragma unroll
    for (int ng = 0; ng < 4; ++ng) U[ig][ng] = f32x4{0.f, 0.f, 0.f, 0.f};
  float ls2[2] = {0.f, 0.f};

  // incremental staging addresses (each thread: 2 V slots + 2 Q slots)
  const int sA = tid, sB = 512 + tid;
  const bf16_t* vgA = VTb + (long)(sA >> 4) * 1024 + (((sA & 15) ^ ((sA >> 4) & 15)) << 3);
  const bf16_t* vgB = VTb + (long)(sB >> 4) * 1024 + (((sB & 15) ^ ((sB >> 4) & 15)) << 3);
  const bf16_t* qgA = Qb + (long)(sA >> 3) * 2048 + (((sA & 7) ^ ((sA >> 3) & 7)) << 3);
  const bf16_t* qgB = Qb + (long)(sB >> 3) * 2048 + (((sB & 7) ^ ((sB >> 3) & 7)) << 3);

  auto stage = [&](int bb) {
    gl_lds16(vgA, &sV[bb][sA * 8]);
    gl_lds16(qgA, &sQ[bb][sA * 8]);
    gl_lds16(vgB, &sV[bb][sB * 8]);
    gl_lds16(qgB, &sQ[bb][sB * 8]);
    vgA += 65536; vgB += 65536;   // 64 rows * 1024
    qgA += 64;    qgB += 64;      // 64 cols
  };

  stage(0);
  __syncthreads();

  for (int jt = 0; jt < 32; jt += 2) {
    #pragma unroll
    for (int half = 0; half < 2; ++half) {     // fully unrolled: half is constant
      const int n = jt + half;
      if (n < 31) stage(half ^ 1);             // prefetch into free buffer

      // ---- S-phase: S^T tiles [j0w+mg*16)[i0w+ng*16)
      const bf16_t* sVc = sV[half];
      #pragma unroll
      for (int mg = 0; mg < 2; ++mg) {
        const int j = j0w + mg * 16 + l15;
        bf16x8 av[4];
        #pragma unroll
        for (int kc = 0; kc < 4; ++kc)
          av[kc] = *(const bf16x8*)&sVc[j * 128 + (((kc * 4 + quad) ^ l15) << 3)];
        #pragma unroll
        for (int ng = 0; ng < 2; ++ng) {
          f32x4 S = f32x4{0.f, 0.f, 0.f, 0.f};
          #pragma unroll
          for (int kc = 0; kc < 4; ++kc)
            S = __builtin_amdgcn_mfma_f32_16x16x32_bf16(av[kc], kf[ng][kc], S, 0, 0, 0);
          // D: row j = j0w+mg*16+quad*4+r, col i = i0w+ng*16+l15 ; K pre-scaled
          bf16x4 p4;
          #pragma unroll
          for (int r = 0; r < 4; ++r) {
            float p = __builtin_amdgcn_exp2f(S[r]);
            ls2[ng] += p;
            p4[r] = (bf16_t)p;
          }
          const int i = i0w + ng * 16 + l15;
          const int jw = j0w + mg * 16 + quad * 4;
          *(bf16x4*)&sP[i * 64 + (((jw >> 3) ^ (i & 7)) << 3) + (jw & 7)] = p4;
        }
      }
      __syncthreads();   // P visible to all waves

      // ---- U-phase: U tiles [i0w+ig*16)[c0+ng*16), k = 64 j
      const bf16_t* sQc = sQ[half];
      #pragma unroll
      for (int kj = 0; kj < 2; ++kj) {
        bf16x8 pa[2];
        #pragma unroll
        for (int ig = 0; ig < 2; ++ig) {
          const int i = i0w + ig * 16 + l15;
          pa[ig] = *(const bf16x8*)&sP[i * 64 + (((kj * 4 + quad) ^ (i & 7)) << 3)];
        }
        #pragma unroll
        for (int ng = 0; ng < 4; ++ng) {
          const int c = c0 + ng * 16 + l15;
          bf16x8 qf = *(const bf16x8*)&sQc[c * 64 + (((kj * 4 + quad) ^ (c & 7)) << 3)];
          #pragma unroll
          for (int ig = 0; ig < 2; ++ig)
            U[ig][ng] = __builtin_amdgcn_mfma_f32_16x16x32_bf16(pa[ig], qf, U[ig][ng], 0, 0, 0);
        }
      }
      __syncthreads();   // release sV/sQ[half] for restage, sP for next S-phase
    }
  }

  // ---- softmax denominators: ls2[ng] partial for i = i0w+ng*16+l15 over jg's j
  #pragma unroll
  for (int ng = 0; ng < 2; ++ng) {
    ls2[ng] += __shfl_xor(ls2[ng], 16, 64);
    ls2[ng] += __shfl_xor(ls2[ng], 32, 64);
  }
  float* lsb = (float*)sP;   // [jg 2][i 128]
  if (lane < 16) {
    lsb[jg * 128 + i0w + lane] = ls2[0];
    lsb[jg * 128 + i0w + 16 + lane] = ls2[1];
  }
  __syncthreads();

  // ---- epilogue: out[b][h*128+c][i0+i], f32x4 along i
  #pragma unroll
  for (int ig = 0; ig < 2; ++ig) {
    f32x4 rcp;
    #pragma unroll
    for (int r = 0; r < 4; ++r) {
      const int i = i0w + ig * 16 + quad * 4 + r;
      rcp[r] = 1.0f / (lsb[i] + lsb[128 + i]);
    }
    #pragma unroll
    for (int ng = 0; ng < 4; ++ng) {
      const int c = h * 128 + c0 + ng * 16 + l15;
      f32x4 v;
      #pragma unroll
      for (int r = 0; r < 4; ++r) v[r] = U[ig][ng][r] * rcp[r];
      const long o = ((long)b * 1024 + c) * 2048 + i0 + i0w + ig * 16 + quad * 4;
      *(f32x4*)&out[o] = v;
    }
  }
}

extern "C" void kernel_launch(void* const* d_in, const int* in_sizes, int n_in,
                              void* d_out, int out_size, void* d_ws, size_t ws_size,
                              hipStream_t stream)
{
  (void)in_sizes; (void)n_in; (void)out_size; (void)ws_size;
  const float* Xq = (const float*)d_in[0];
  const float* Xk = (const float*)d_in[1];
  const float* Wq = (const float*)d_in[2];
  const float* Wk = (const float*)d_in[3];
  const float* Wv = (const float*)d_in[4];
  bf16_t* ws = (bf16_t*)d_ws;
  float* out = (float*)d_out;

  k_wconv<<<dim3(1024, 3), 256, 0, stream>>>(Wq, Wk, Wv, ws);
  k_transpose<<<dim3(32, 16, 8), 256, 0, stream>>>(Xq, Xk, ws);
  k_qkv<<<dim3(16, 8, 12), 256, 0, stream>>>(
      (const float*)d_in[5],  (const float*)d_in[6],  (const float*)d_in[7],  (const float*)d_in[8],
      (const float*)d_in[9],  (const float*)d_in[10], (const float*)d_in[11], (const float*)d_in[12],
      (const float*)d_in[13], (const float*)d_in[14], (const float*)d_in[15], (const float*)d_in[16],
      ws);
  k_attn<<<dim3(16, 8, 4), 512, 0, stream>>>(ws, out);
}

// Round 7
// 288.057 us; speedup vs baseline: 1.0381x; 1.0314x over previous
//
#include <hip/hip_runtime.h>

typedef __bf16 bf16_t;
typedef __bf16 bf16x8 __attribute__((ext_vector_type(8)));
typedef __bf16 bf16x4 __attribute__((ext_vector_type(4)));
typedef float  f32x4  __attribute__((ext_vector_type(4)));

// workspace layout (bf16 element offsets)
#define WB_OFF  0LL          // 3 x 1024 x 1024 bf16 weights (q,k,v)
#define XQT_OFF 3145728LL    // [b][p][c] bf16
#define XKT_OFF 11534336LL
#define Q_OFF   19922944LL   // [b][c][p] bf16
#define KT_OFF  28311552LL   // [b][p][c] bf16 (pre-scaled by log2(e)/sqrt(128))
#define VT_OFF  36700160LL   // [b][p][c] bf16
// total: 45088768 elems * 2B = 90.2 MB

__device__ __forceinline__ void gl_lds16(const bf16_t* g, bf16_t* l) {
  __builtin_amdgcn_global_load_lds((const __attribute__((address_space(1))) void*)(g),
                                   (__attribute__((address_space(3))) void*)(l), 16, 0, 0);
}

__device__ __forceinline__ bf16x4 cvt4(f32x4 v) {
  bf16x4 r;
  r[0] = (bf16_t)v[0]; r[1] = (bf16_t)v[1]; r[2] = (bf16_t)v[2]; r[3] = (bf16_t)v[3];
  return r;
}

#define ATT_SCL 0.1275973836582966f   // log2(e) / sqrt(128), folded into K branch

// barrier variants: barrier 1 of the jt loop only needs LDS (ds_write P) to be
// visible -- the in-flight global_load_lds prefetch targets the OTHER LDS
// buffer, so draining vmcnt there (what __syncthreads does) serializes the
// pipeline for nothing. Full drain happens once per jt at barrier 2, by which
// point the prefetch has had the whole S+U phase to land.
#define BAR_LGKM() asm volatile("s_waitcnt lgkmcnt(0)\n\ts_barrier" ::: "memory")
#define BAR_FULL() asm volatile("s_waitcnt vmcnt(0) lgkmcnt(0)\n\ts_barrier" ::: "memory")

// ---------------- weight convert: fp32 -> bf16 ----------------
__global__ __launch_bounds__(256) void k_wconv(
    const float* __restrict__ Wq, const float* __restrict__ Wk, const float* __restrict__ Wv,
    bf16_t* __restrict__ ws)
{
  const float* W = blockIdx.y == 0 ? Wq : (blockIdx.y == 1 ? Wk : Wv);
  bf16_t* dst = ws + WB_OFF + (long)blockIdx.y * 1048576;
  const long i = ((long)blockIdx.x * 256 + threadIdx.x) * 4;
  *(bf16x4*)&dst[i] = cvt4(*(const f32x4*)(W + i));
}

// ---------------- transpose+convert: XT[b][p][c] = bf16(X[b][c][p]) ----------------
__global__ __launch_bounds__(256) void k_transpose(
    const float* __restrict__ Xq, const float* __restrict__ Xk, bf16_t* __restrict__ ws)
{
  __shared__ __align__(16) bf16_t t[64 * 72];  // +8 pad per row (16B-aligned rows)
  const int z = blockIdx.z, b = z & 3, ts = z >> 2;
  const float* X = ts ? Xk : Xq;
  bf16_t* XT = ws + (ts ? XKT_OFF : XQT_OFF);
  const int p0 = blockIdx.x * 64, c0 = blockIdx.y * 64;
  const int tid = threadIdx.x;
  const int tx = tid & 15, ty = tid >> 4;  // tx: float4 column, ty: 0..15
  const float* src = X + ((long)b * 1024 + c0) * 2048 + p0;
  #pragma unroll
  for (int hh = 0; hh < 4; ++hh) {
    int c = ty + hh * 16;
    f32x4 v = *(const f32x4*)(src + (long)c * 2048 + tx * 4);
    *(bf16x4*)&t[c * 72 + tx * 4] = cvt4(v);
  }
  __syncthreads();
  bf16_t* dst = XT + ((long)b * 2048 + p0) * 1024 + c0;
  #pragma unroll
  for (int hh = 0; hh < 2; ++hh) {
    int p = (tid >> 3) + hh * 32;  // 0..63
    int cc = tid & 7;
    bf16x8 v;
    #pragma unroll
    for (int j = 0; j < 8; ++j) v[j] = t[(cc * 8 + j) * 72 + p];
    *(bf16x8*)(dst + (long)p * 1024 + cc * 8) = v;
  }
}

// ---------------- QKV GEMM: Y[o][p] = LeakyReLU(BN(W @ X)) ----------------
__global__ __launch_bounds__(256) void k_qkv(
    const float* __restrict__ g1, const float* __restrict__ b1, const float* __restrict__ m1, const float* __restrict__ v1,
    const float* __restrict__ g2, const float* __restrict__ b2, const float* __restrict__ m2, const float* __restrict__ v2,
    const float* __restrict__ g3, const float* __restrict__ b3, const float* __restrict__ m3, const float* __restrict__ v3,
    bf16_t* __restrict__ ws)
{
  __shared__ __align__(16) bf16_t smem[17408];  // staging: a[8192]+b[8192]; epilogue: 128*136
  bf16_t* sa = smem;
  bf16_t* sb = smem + 8192;
  bf16_t* ep = smem;
  __shared__ float sS[128], sBi[128];

  const int tid = threadIdx.x;
  const int z = blockIdx.z, br = z >> 2, b = z & 3;
  const int o0 = blockIdx.y * 128, p0 = blockIdx.x * 128;

  const float *gm, *bt, *mn, *vr;
  const bf16_t *XT;
  bf16_t* dst;
  int tr;
  if (br == 0)      { XT = ws + XQT_OFF; gm = g1; bt = b1; mn = m1; vr = v1; dst = ws + Q_OFF;  tr = 0; }
  else if (br == 1) { XT = ws + XKT_OFF; gm = g2; bt = b2; mn = m2; vr = v2; dst = ws + KT_OFF; tr = 1; }
  else              { XT = ws + XQT_OFF; gm = g3; bt = b3; mn = m3; vr = v3; dst = ws + VT_OFF; tr = 1; }
  const bf16_t* W = ws + WB_OFF + (long)br * 1048576;

  if (tid < 128) {
    float g = gm[o0 + tid], be = bt[o0 + tid];
    float m = mn[o0 + tid], v = vr[o0 + tid];
    float sc = g / sqrtf(v + 1e-5f);
    float bi = be - m * sc;
    if (br == 1) { sc *= ATT_SCL; bi *= ATT_SCL; }   // fold attn scale into K branch
    sS[tid] = sc; sBi[tid] = bi;
  }

  const int w = tid >> 6, lane = tid & 63, quad = lane >> 4, l15 = lane & 15;
  const int wr = (w >> 1) * 64, wc = (w & 1) * 64;

  f32x4 acc[4][4];
  #pragma unroll
  for (int i = 0; i < 4; ++i)
    #pragma unroll
    for (int j = 0; j < 4; ++j) acc[i][j] = f32x4{0.f, 0.f, 0.f, 0.f};

  const bf16_t* Wb = W + (long)o0 * 1024;
  const bf16_t* Xb = XT + ((long)b * 2048 + p0) * 1024;

  for (int kk = 0; kk < 16; ++kk) {
    __syncthreads();
    const int kof = kk * 64;
    #pragma unroll
    for (int is = 0; is < 4; ++is) {
      int s = (is * 4 + w) * 64 + lane;
      int row = s >> 3, ch = s & 7;
      int col = kof + ((ch ^ (row & 7)) << 3);
      gl_lds16(Wb + (long)row * 1024 + col, &sa[(is * 4 + w) * 512]);
      gl_lds16(Xb + (long)row * 1024 + col, &sb[(is * 4 + w) * 512]);
    }
    __syncthreads();
    #pragma unroll
    for (int ks = 0; ks < 2; ++ks) {
      bf16x8 af[4], bfr[4];
      #pragma unroll
      for (int i = 0; i < 4; ++i) {
        int mm = wr + i * 16 + l15;
        af[i] = *(const bf16x8*)&sa[mm * 64 + (((ks * 4 + quad) ^ (mm & 7)) << 3)];
        int nn = wc + i * 16 + l15;
        bfr[i] = *(const bf16x8*)&sb[nn * 64 + (((ks * 4 + quad) ^ (nn & 7)) << 3)];
      }
      #pragma unroll
      for (int i = 0; i < 4; ++i)
        #pragma unroll
        for (int j = 0; j < 4; ++j)
          acc[i][j] = __builtin_amdgcn_mfma_f32_16x16x32_bf16(af[i], bfr[j], acc[i][j], 0, 0, 0);
    }
  }

  __syncthreads();
  #pragma unroll
  for (int i = 0; i < 4; ++i) {
    #pragma unroll
    for (int j = 0; j < 4; ++j) {
      const int p_l = wc + j * 16 + l15;
      const int ob = wr + i * 16 + quad * 4;
      if (!tr) {
        #pragma unroll
        for (int r = 0; r < 4; ++r) {
          float v = fmaf(acc[i][j][r], sS[ob + r], sBi[ob + r]);
          v = v > 0.f ? v : 0.1f * v;
          ep[(ob + r) * 136 + p_l] = (bf16_t)v;
        }
      } else {
        bf16x4 t4;
        #pragma unroll
        for (int r = 0; r < 4; ++r) {
          float v = fmaf(acc[i][j][r], sS[ob + r], sBi[ob + r]);
          v = v > 0.f ? v : 0.1f * v;
          t4[r] = (bf16_t)v;
        }
        *(bf16x4*)&ep[p_l * 136 + ob] = t4;  // (p_l*136+ob)*2 is 8B-aligned
      }
    }
  }
  __syncthreads();
  #pragma unroll
  for (int pass = 0; pass < 8; ++pass) {
    int row = pass * 16 + (tid >> 4);
    int ch = tid & 15;
    bf16x8 v = *(const bf16x8*)&ep[row * 136 + ch * 8];
    long off;
    if (!tr) off = ((long)b * 1024 + o0 + row) * 2048 + p0 + ch * 8;
    else     off = ((long)b * 2048 + p0 + row) * 1024 + o0 + ch * 8;
    *(bf16x8*)&dst[off] = v;
  }
}

// ---------------- fused attention v5: async barriers + XCD locality ----------------
// v4 tiling (S^T 32x32/wave, U 32x64/wave). Barrier 1 is lgkmcnt-only so the
// V/Q prefetch stays in flight across the whole jt body (drained once at
// barrier 2). Grid is 1-D with bh in the low 5 bits: all 16 i-tile blocks of
// one (b,h) land on the same XCD (round-robin n%8) -> V/Q become L2-resident.
__global__ __launch_bounds__(512) __attribute__((amdgpu_waves_per_eu(4, 4)))
void k_attn(const bf16_t* __restrict__ ws, float* __restrict__ out)
{
  __shared__ __align__(16) bf16_t sV[2][8192];   // [j 64][c 128] chunk-swizzled
  __shared__ __align__(16) bf16_t sQ[2][8192];   // [c 128][j 64] chunk-swizzled
  __shared__ __align__(16) bf16_t sP[8192];      // [i 128][j 64] chunk-swizzled

  const int tid = threadIdx.x, w = tid >> 6, lane = tid & 63, quad = lane >> 4, l15 = lane & 15;
  // XCD-locality swizzle: bh fastest -> all it-blocks of a (b,h) share an XCD
  const int bh = blockIdx.x & 31, it = blockIdx.x >> 5;
  const int b = bh >> 3, h = bh & 7, i0 = it * 128;

  const bf16_t* KTb = ws + KT_OFF + ((long)b * 2048 + i0) * 1024 + h * 128;
  const bf16_t* VTb = ws + VT_OFF + ((long)b * 2048) * 1024 + h * 128;
  const bf16_t* Qb  = ws + Q_OFF  + ((long)b * 1024 + h * 128) * 2048;

  const int iq = w & 3, jg = w >> 2;
  const int i0w = iq * 32, j0w = jg * 32, c0 = jg * 64;

  // resident K B-frags: kf[ng][kc] covers i = i0w+ng*16+l15, c = kc*32+quad*8+e
  bf16x8 kf[2][4];
  #pragma unroll
  for (int ng = 0; ng < 2; ++ng) {
    const bf16_t* kr = KTb + (long)(i0w + ng * 16 + l15) * 1024 + quad * 8;
    #pragma unroll
    for (int kc = 0; kc < 4; ++kc)
      kf[ng][kc] = *(const bf16x8*)(kr + kc * 32);
  }

  f32x4 U[2][4];
  #pragma unroll
  for (int ig = 0; ig < 2; ++ig)
    #pragma unroll
    for (int ng = 0; ng < 4; ++ng) U[ig][ng] = f32x4{0.f, 0.f, 0.f, 0.f};
  float ls2[2] = {0.f, 0.f};

  // incremental staging addresses (each thread: 2 V slots + 2 Q slots)
  const int sA = tid, sB = 512 + tid;
  const bf16_t* vgA = VTb + (long)(sA >> 4) * 1024 + (((sA & 15) ^ ((sA >> 4) & 15)) << 3);
  const bf16_t* vgB = VTb + (long)(sB >> 4) * 1024 + (((sB & 15) ^ ((sB >> 4) & 15)) << 3);
  const bf16_t* qgA = Qb + (long)(sA >> 3) * 2048 + (((sA & 7) ^ ((sA >> 3) & 7)) << 3);
  const bf16_t* qgB = Qb + (long)(sB >> 3) * 2048 + (((sB & 7) ^ ((sB >> 3) & 7)) << 3);

  auto stage = [&](int bb) {
    gl_lds16(vgA, &sV[bb][sA * 8]);
    gl_lds16(qgA, &sQ[bb][sA * 8]);
    gl_lds16(vgB, &sV[bb][sB * 8]);
    gl_lds16(qgB, &sQ[bb][sB * 8]);
    vgA += 65536; vgB += 65536;   // 64 rows * 1024
    qgA += 64;    qgB += 64;      // 64 cols
  };

  stage(0);
  BAR_FULL();

  for (int jt = 0; jt < 32; jt += 2) {
    #pragma unroll
    for (int half = 0; half < 2; ++half) {     // fully unrolled: half is constant
      const int n = jt + half;
      if (n < 31) stage(half ^ 1);             // prefetch; stays in flight past barrier 1

      // ---- S-phase: S^T tiles [j0w+mg*16)[i0w+ng*16)
      const bf16_t* sVc = sV[half];
      #pragma unroll
      for (int mg = 0; mg < 2; ++mg) {
        const int j = j0w + mg * 16 + l15;
        bf16x8 av[4];
        #pragma unroll
        for (int kc = 0; kc < 4; ++kc)
          av[kc] = *(const bf16x8*)&sVc[j * 128 + (((kc * 4 + quad) ^ l15) << 3)];
        #pragma unroll
        for (int ng = 0; ng < 2; ++ng) {
          f32x4 S = f32x4{0.f, 0.f, 0.f, 0.f};
          #pragma unroll
          for (int kc = 0; kc < 4; ++kc)
            S = __builtin_amdgcn_mfma_f32_16x16x32_bf16(av[kc], kf[ng][kc], S, 0, 0, 0);
          // D: row j = j0w+mg*16+quad*4+r, col i = i0w+ng*16+l15 ; K pre-scaled
          bf16x4 p4;
          #pragma unroll
          for (int r = 0; r < 4; ++r) {
            float p = __builtin_amdgcn_exp2f(S[r]);
            ls2[ng] += p;
            p4[r] = (bf16_t)p;
          }
          const int i = i0w + ng * 16 + l15;
          const int jw = j0w + mg * 16 + quad * 4;
          *(bf16x4*)&sP[i * 64 + (((jw >> 3) ^ (i & 7)) << 3) + (jw & 7)] = p4;
        }
      }
      BAR_LGKM();        // P visible; prefetch still in flight (targets other buffer)

      // ---- U-phase: U tiles [i0w+ig*16)[c0+ng*16), k = 64 j
      const bf16_t* sQc = sQ[half];
      #pragma unroll
      for (int kj = 0; kj < 2; ++kj) {
        bf16x8 pa[2];
        #pragma unroll
        for (int ig = 0; ig < 2; ++ig) {
          const int i = i0w + ig * 16 + l15;
          pa[ig] = *(const bf16x8*)&sP[i * 64 + (((kj * 4 + quad) ^ (i & 7)) << 3)];
        }
        #pragma unroll
        for (int ng = 0; ng < 4; ++ng) {
          const int c = c0 + ng * 16 + l15;
          bf16x8 qf = *(const bf16x8*)&sQc[c * 64 + (((kj * 4 + quad) ^ (c & 7)) << 3)];
          #pragma unroll
          for (int ig = 0; ig < 2; ++ig)
            U[ig][ng] = __builtin_amdgcn_mfma_f32_16x16x32_bf16(pa[ig], qf, U[ig][ng], 0, 0, 0);
        }
      }
      BAR_FULL();        // prefetch landed (had S+U to fly); buffers rotate
    }
  }

  // ---- softmax denominators: ls2[ng] partial for i = i0w+ng*16+l15 over jg's j
  #pragma unroll
  for (int ng = 0; ng < 2; ++ng) {
    ls2[ng] += __shfl_xor(ls2[ng], 16, 64);
    ls2[ng] += __shfl_xor(ls2[ng], 32, 64);
  }
  float* lsb = (float*)sP;   // [jg 2][i 128]
  if (lane < 16) {
    lsb[jg * 128 + i0w + lane] = ls2[0];
    lsb[jg * 128 + i0w + 16 + lane] = ls2[1];
  }
  __syncthreads();

  // ---- epilogue: out[b][h*128+c][i0+i], f32x4 along i
  #pragma unroll
  for (int ig = 0; ig < 2; ++ig) {
    f32x4 rcp;
    #pragma unroll
    for (int r = 0; r < 4; ++r) {
      const int i = i0w + ig * 16 + quad * 4 + r;
      rcp[r] = 1.0f / (lsb[i] + lsb[128 + i]);
    }
    #pragma unroll
    for (int ng = 0; ng < 4; ++ng) {
      const int c = h * 128 + c0 + ng * 16 + l15;
      f32x4 v;
      #pragma unroll
      for (int r = 0; r < 4; ++r) v[r] = U[ig][ng][r] * rcp[r];
      const long o = ((long)b * 1024 + c) * 2048 + i0 + i0w + ig * 16 + quad * 4;
      *(f32x4*)&out[o] = v;
    }
  }
}

extern "C" void kernel_launch(void* const* d_in, const int* in_sizes, int n_in,
                              void* d_out, int out_size, void* d_ws, size_t ws_size,
                              hipStream_t stream)
{
  (void)in_sizes; (void)n_in; (void)out_size; (void)ws_size;
  const float* Xq = (const float*)d_in[0];
  const float* Xk = (const float*)d_in[1];
  const float* Wq = (const float*)d_in[2];
  const float* Wk = (const float*)d_in[3];
  const float* Wv = (const float*)d_in[4];
  bf16_t* ws = (bf16_t*)d_ws;
  float* out = (float*)d_out;

  k_wconv<<<dim3(1024, 3), 256, 0, stream>>>(Wq, Wk, Wv, ws);
  k_transpose<<<dim3(32, 16, 8), 256, 0, stream>>>(Xq, Xk, ws);
  k_qkv<<<dim3(16, 8, 12), 256, 0, stream>>>(
      (const float*)d_in[5],  (const float*)d_in[6],  (const float*)d_in[7],  (const float*)d_in[8],
      (const float*)d_in[9],  (const float*)d_in[10], (const float*)d_in[11], (const float*)d_in[12],
      (const float*)d_in[13], (const float*)d_in[14], (const float*)d_in[15], (const float*)d_in[16],
      ws);
  k_attn<<<512, 512, 0, stream>>>(ws, out);
}